// Round 11
// baseline (243.360 us; speedup 1.0000x reference)
//
#include <hip/hip_runtime.h>

// ---- problem constants (from reference) ----
#define N_NODES   100000
#define T_TYPES   4
#define E_EDGES   400000
#define E4        100000                    // int4 groups per type-array
#define G_TOT     400000                    // total int4 groups = TE_TOT/4
#define C_CH      2
#define W_INF     128
#define DD        64
#define NUM_CLASS 16
#define BETA      0.5f
#define M_TGT     10000

// CSR build tiling: 256-row buckets (partition), 32-row octants (sort/gather)
#define NBKT      391                       // ceil(100000/256) buckets of 256 rows
#define BROWS     256
#define BPAD      4864                      // unsorted slots/bucket (mean 4096 +12 sigma)
#define QPAD      672                       // sorted slots/octant (mean 512 +7 sigma)
#define CHUNK_G   1024                      // int4 groups per partition block (4096 edges)
#define NPART_BLK 391                      // ceil(400000/1024): min cursor contention
#define PROJ_BLK  1563                      // ceil(100000/64)
#define SROUND    1024                      // staged-flush slots per round (4 rounds)
#define NCNT      100032                    // istgt/need array size (64-padded)

// bf16 planes: u32 at [n*64 + d] = bf16(ch0) | bf16(ch1)<<16
static const size_t PLANE2 = (size_t)N_NODES * DD;    // u32 elements per plane

typedef __attribute__((ext_vector_type(8))) short short8x;   // 8 bf16 (4 VGPRs)
typedef __attribute__((ext_vector_type(4))) float f32x4;     // MFMA C/D

__device__ __forceinline__ unsigned bf16rne(float x) {   // RNE f32 -> bf16 bits
    unsigned u = __float_as_uint(x);
    return (u + 0x7FFFu + ((u >> 16) & 1u)) >> 16;
}
__device__ __forceinline__ unsigned packbf(float a, float b) {
    return bf16rne(a) | (bf16rne(b) << 16);
}
__device__ __forceinline__ float bflo(unsigned u) { return __uint_as_float(u << 16); }
__device__ __forceinline__ float bfhi(unsigned u) { return __uint_as_float(u & 0xFFFF0000u); }

__device__ __forceinline__ void load_filter(const float* cw, int layer,
                                            float* f0, float* f1) {
    float m0 = -1e30f, m1 = -1e30f;
    #pragma unroll
    for (int t = 0; t < T_TYPES; ++t) {
        f0[t] = cw[layer * C_CH * T_TYPES + t];
        f1[t] = cw[layer * C_CH * T_TYPES + T_TYPES + t];
        m0 = fmaxf(m0, f0[t]); m1 = fmaxf(m1, f1[t]);
    }
    float s0 = 0.f, s1 = 0.f;
    #pragma unroll
    for (int t = 0; t < T_TYPES; ++t) {
        f0[t] = __expf(f0[t] - m0); s0 += f0[t];
        f1[t] = __expf(f1[t] - m1); s1 += f1[t];
    }
    #pragma unroll
    for (int t = 0; t < T_TYPES; ++t) { f0[t] /= s0; f1[t] /= s1; }
}

// ---------------------------------------------------------------------------
// prep: Wsb (blocks 0..63) + cursor init (64..65) + istgt fill (66..105).
// istgt[] / need[] are zeroed by hipMemsetAsync before this kernel.
// ---------------------------------------------------------------------------
__global__ void prep_kernel(const float* __restrict__ Ws,
                            unsigned short* __restrict__ Wsb,
                            int* __restrict__ cursor,
                            const int* __restrict__ tgt,
                            int* __restrict__ istgt) {
    int b = blockIdx.x;
    int tid = threadIdx.x;
    if (b < 64) {
        int idx = b * 256 + tid;
        int c   = idx >> 13;
        int rem = idx & 8191;
        int d   = rem >> 7;
        int k   = rem & 127;
        Wsb[idx] = (unsigned short)bf16rne(Ws[c * (W_INF * DD) + k * DD + d]);
    } else if (b < 66) {
        int idx = (b - 64) * 256 + tid;
        if (idx < NBKT) cursor[idx] = idx * BPAD;
    } else {
        int idx = (b - 66) * 256 + tid;
        if (idx < M_TGT) istgt[tgt[idx]] = 1;
    }
}

// ---------------------------------------------------------------------------
// Fused: blocks [0, NPART_BLK) partition 4096 edges each into 256-row buckets.
// FOUR-ROUND LDS staging (1024-slot buffer reused), ~15 KB LDS -> 8 blocks/CU.
// NEW (round 11): the flush loop marks need[col]=1 for edges whose destination
// row is a target (istgt lookup, L2-resident; independent iterations so the
// latency hides) -- the needed-H1 set for sortgather's gather skip.
// Blocks [NPART_BLK, +PROJ_BLK) run the LDS-free MFMA projection.
// record: edata2[pos] = { col | t<<17 | (row&255)<<19 ,
//                         packbf(val*f0_l1[t], val*f1_l1[t]) }
// ---------------------------------------------------------------------------
__global__ __launch_bounds__(256) void build_proj_kernel(
        const int* __restrict__ edge_index,
        const float* __restrict__ edge_value,
        const float* __restrict__ cw,
        int* __restrict__ cursor,
        int2* __restrict__ edata2,
        const float* __restrict__ X,
        const unsigned short* __restrict__ Wsb,
        unsigned* __restrict__ Xp16,
        const int* __restrict__ istgt,
        int* __restrict__ need) {
    __shared__ int cnt[392];
    __shared__ int lbase[392];
    __shared__ int gbase[392];
    __shared__ int2 le[SROUND];                   // 8 KB (reused per round)
    __shared__ unsigned short lbk[SROUND];        // 2 KB
    int tid = threadIdx.x;

    if (blockIdx.x < NPART_BLK) {
        // ---------------- partition ----------------
        int p = blockIdx.x;
        for (int j = tid; j < NBKT; j += 256) cnt[j] = 0;
        __syncthreads();

        float f0[T_TYPES], f1[T_TYPES];
        load_filter(cw, 0, f0, f1);

        int px[16], pv[16], rk[16], bk[16];
        int ne = 0;
        #pragma unroll
        for (int g = 0; g < 4; ++g) {
            int idx = p * CHUNK_G + g * 256 + tid;
            if (idx < G_TOT) {
                int t = idx / E4, r = idx - t * E4;
                const int* bptr = edge_index + (size_t)t * 2 * E_EDGES;
                int4   rw = ((const int4*)bptr)[r];
                int4   cl = ((const int4*)(bptr + E_EDGES))[r];
                float4 vv = ((const float4*)(edge_value + (size_t)t * E_EDGES))[r];
                int tb = t << 17;
                int   rr[4] = {rw.x, rw.y, rw.z, rw.w};
                int   cc[4] = {cl.x, cl.y, cl.z, cl.w};
                float vf[4] = {vv.x, vv.y, vv.z, vv.w};
                #pragma unroll
                for (int k = 0; k < 4; ++k) {
                    int b = rr[k] >> 8;
                    px[ne] = cc[k] | tb | ((rr[k] & 255) << 19);
                    pv[ne] = __float_as_int(vf[k]);
                    bk[ne] = b;
                    rk[ne] = atomicAdd(&cnt[b], 1);
                    ++ne;
                }
            }
        }
        __syncthreads();
        if (tid < 64) {                                // scan cnt -> lbase (7/lane)
            int c[7]; int s = 0;
            #pragma unroll
            for (int k = 0; k < 7; ++k) {
                int idx = tid * 7 + k;
                c[k] = (idx < NBKT) ? cnt[idx] : 0;
                s += c[k];
            }
            int inc = s;
            #pragma unroll
            for (int off = 1; off < 64; off <<= 1) {
                int v = __shfl_up(inc, off);
                if (tid >= off) inc += v;
            }
            int base = inc - s;
            #pragma unroll
            for (int k = 0; k < 7; ++k) {
                int idx = tid * 7 + k;
                if (idx < NBKT) lbase[idx] = base;
                base += c[k];
            }
        }
        __syncthreads();
        for (int j = tid; j < NBKT; j += 256)
            gbase[j] = cnt[j] ? atomicAdd(&cursor[j], cnt[j]) : 0;
        __syncthreads();

        int ngrp = min(CHUNK_G, G_TOT - p * CHUNK_G);
        int nloc = 4 * ngrp;
        #pragma unroll
        for (int rd = 0; rd < 4; ++rd) {
            int lo = rd * SROUND;
            // stage this round's slot range
            #pragma unroll
            for (int k = 0; k < 16; ++k) {
                if (k < ne) {
                    int slot = lbase[bk[k]] + rk[k] - lo;
                    if ((unsigned)slot < (unsigned)SROUND) {
                        le[slot]  = make_int2(px[k], pv[k]);
                        lbk[slot] = (unsigned short)bk[k];
                    }
                }
            }
            __syncthreads();
            int nthis = min(SROUND, nloc - lo);
            for (int j = tid; j < nthis; j += 256) {
                int bkt = lbk[j];
                int2 e = le[j];
                int t = (e.x >> 17) & 3;
                float v = __int_as_float(e.y);
                int row = (bkt << 8) | ((e.x >> 19) & 255);
                if (istgt[row]) need[e.x & 0x1FFFF] = 1;
                edata2[gbase[bkt] + (lo + j - lbase[bkt])] =
                    make_int2(e.x, (int)packbf(v * f0[t], v * f1[t]));
            }
            __syncthreads();
        }
    } else {
        // ---------------- MFMA projection (LDS-free) ----------------
        int row0 = (blockIdx.x - NPART_BLK) * 64;
        int wave = tid >> 6, lane = tid & 63;
        int m = lane & 15, q = lane >> 4;
        int arow = row0 + wave * 16 + m;
        const float4* X4 = (const float4*)X;
        union { short8x s; uint4 u; } A[4];
        bool valid = arow < N_NODES;
        #pragma unroll
        for (int ks = 0; ks < 4; ++ks) {
            float4 va = make_float4(0.f, 0.f, 0.f, 0.f), vb = va;
            if (valid) {
                va = X4[(size_t)arow * 32 + ks * 8 + q * 2];
                vb = X4[(size_t)arow * 32 + ks * 8 + q * 2 + 1];
            }
            A[ks].u = make_uint4(packbf(va.x, va.y), packbf(va.z, va.w),
                                 packbf(vb.x, vb.y), packbf(vb.z, vb.w));
        }

        #pragma unroll
        for (int ct = 0; ct < 4; ++ct) {
            f32x4 acc0 = {0.f, 0.f, 0.f, 0.f};
            f32x4 acc1 = {0.f, 0.f, 0.f, 0.f};
            #pragma unroll
            for (int ks = 0; ks < 4; ++ks) {
                short8x B0 = *(const short8x*)(Wsb + (ct * 16 + m) * 128 + ks * 32 + q * 8);
                short8x B1 = *(const short8x*)(Wsb + 8192 + (ct * 16 + m) * 128 + ks * 32 + q * 8);
                acc0 = __builtin_amdgcn_mfma_f32_16x16x32_bf16(A[ks].s, B0, acc0, 0, 0, 0);
                acc1 = __builtin_amdgcn_mfma_f32_16x16x32_bf16(A[ks].s, B1, acc1, 0, 0, 0);
            }
            #pragma unroll
            for (int r = 0; r < 4; ++r) {
                int row = row0 + wave * 16 + q * 4 + r;
                if (row < N_NODES)
                    Xp16[(size_t)row * DD + ct * 16 + m] = packbf(acc0[r], acc1[r]);
            }
        }
    }
}

// ---------------------------------------------------------------------------
// Quarter-wave bf16 gather helpers
// ---------------------------------------------------------------------------
__device__ __forceinline__ void qfma(const uint4 h, unsigned wp,
                                     float4& a, float4& b) {
    float w0 = bflo(wp), w1 = bfhi(wp);
    a.x = fmaf(w0, bflo(h.x), a.x);
    a.y = fmaf(w1, bfhi(h.x), a.y);
    a.z = fmaf(w0, bflo(h.y), a.z);
    a.w = fmaf(w1, bfhi(h.y), a.w);
    b.x = fmaf(w0, bflo(h.z), b.x);
    b.y = fmaf(w1, bfhi(h.z), b.y);
    b.z = fmaf(w0, bflo(h.w), b.z);
    b.w = fmaf(w1, bfhi(h.w), b.w);
}

__device__ __forceinline__ void qreduce(float4& a, float4& b) {
    a.x += __shfl_xor(a.x, 16); a.y += __shfl_xor(a.y, 16);
    a.z += __shfl_xor(a.z, 16); a.w += __shfl_xor(a.w, 16);
    b.x += __shfl_xor(b.x, 16); b.y += __shfl_xor(b.y, 16);
    b.z += __shfl_xor(b.z, 16); b.w += __shfl_xor(b.w, 16);
    a.x += __shfl_xor(a.x, 32); a.y += __shfl_xor(a.y, 32);
    a.z += __shfl_xor(a.z, 32); a.w += __shfl_xor(a.w, 32);
    b.x += __shfl_xor(b.x, 32); b.y += __shfl_xor(b.y, 32);
    b.z += __shfl_xor(b.z, 32); b.w += __shfl_xor(b.w, 32);
}

__device__ __forceinline__ int row_beg(const int* offs, int row) {
    return ((row & 31) == 0) ? (row >> 5) * QPAD : offs[row - 1];
}

// ---------------------------------------------------------------------------
// Per-OCTANT (32 rows of a 256-row bucket) sort + layer-1 gather.
// XCD-affine temporal interleave (round 10). NEW (round 11): rows with
// need[row]==0 (H1 never read by tgt_tail -- not a column of any target-row
// edge, ~22% of rows) skip the gather + H116 store entirely. Sort, edataS
// write-back and offs stay exact for ALL rows (row_beg correctness).
// ---------------------------------------------------------------------------
__global__ __launch_bounds__(256) void sortgather_kernel(
        const int* __restrict__ cursor,
        const int2* __restrict__ edata2,
        int2* __restrict__ edataS,
        int* __restrict__ offs,
        const int* __restrict__ need,
        const unsigned* __restrict__ Hin16,
        unsigned* __restrict__ Hout16) {
    __shared__ int rcnt[32];
    __shared__ int rbase[32];
    __shared__ int rcur[32];
    __shared__ int nq;
    __shared__ int2 ls[QPAD];                     // 5376 B
    __shared__ int2 ls2[QPAD];                    // 5376 B (sorted)
    int i = blockIdx.x;
    int b = (i & 7) + ((i >> 6) << 3);            // bucket: same XCD, 8 consecutive slots
    int o = (i >> 3) & 7;                         // octant
    if (b >= NBKT) return;
    int tid = threadIdx.x;
    int bb  = b * BPAD;
    int cnt = cursor[b] - bb;

    if (tid < 32) rcnt[tid] = 0;
    if (tid == 0) nq = 0;
    __syncthreads();
    for (int j = tid; j < cnt; j += 256) {
        int2 e = edata2[bb + j];
        int rt = (e.x >> 19) & 255;
        if ((rt >> 5) == o) {
            int pos = atomicAdd(&nq, 1);
            if (pos < QPAD) {
                ls[pos] = e;
                atomicAdd(&rcnt[rt & 31], 1);
            }
        }
    }
    __syncthreads();
    int nl = min(nq, QPAD);
    if (tid < 32) {                                // scan 32 row counts (wave 0)
        int c = rcnt[tid];
        int inc = c;
        #pragma unroll
        for (int off = 1; off < 32; off <<= 1) {
            int v = __shfl_up(inc, off);
            if (tid >= off) inc += v;
        }
        rbase[tid] = inc - c;
        rcur[tid]  = inc - c;
    }
    __syncthreads();
    for (int j = tid; j < nl; j += 256) {
        int2 e = ls[j];
        int lr = (e.x >> 19) & 31;
        int pos = atomicAdd(&rcur[lr], 1);
        ls2[pos] = e;
    }
    __syncthreads();

    int s  = b * 8 + o;                           // global 32-row octant id
    int sb = s * QPAD;
    for (int i2 = tid; i2 < nl; i2 += 256)        // coalesced sorted write-back
        edataS[sb + i2] = ls2[i2];
    int row0 = s * 32;
    if (tid < 32 && row0 + tid < N_NODES)
        offs[row0 + tid] = sb + rbase[tid] + rcnt[tid];
    __syncthreads();

    // ---- layer-1 gather: quarter-per-row, need[]-gated ----
    int wv = tid >> 6, lane = tid & 63;
    int s16 = lane & 15, qd = lane >> 4;
    const uint4* hp = (const uint4*)Hin16;
    #pragma unroll
    for (int rr = 0; rr < 2; ++rr) {
        int lr  = wv * 8 + rr * 4 + qd;
        int row = row0 + lr;
        if (row >= N_NODES || !need[row]) continue;   // H1 never consumed
        int beg = rbase[lr];
        int end = beg + rcnt[lr];
        float4 a  = make_float4(0.f, 0.f, 0.f, 0.f);
        float4 b4 = make_float4(0.f, 0.f, 0.f, 0.f);
        int i3 = beg;
        for (; i3 + 3 < end; i3 += 4) {
            int2 e0 = ls2[i3], e1 = ls2[i3 + 1], e2 = ls2[i3 + 2], e3 = ls2[i3 + 3];
            uint4 h0 = hp[(size_t)(e0.x & 0x1FFFF) * 16 + s16];
            uint4 h1 = hp[(size_t)(e1.x & 0x1FFFF) * 16 + s16];
            uint4 h2 = hp[(size_t)(e2.x & 0x1FFFF) * 16 + s16];
            uint4 h3 = hp[(size_t)(e3.x & 0x1FFFF) * 16 + s16];
            qfma(h0, (unsigned)e0.y, a, b4);
            qfma(h1, (unsigned)e1.y, a, b4);
            qfma(h2, (unsigned)e2.y, a, b4);
            qfma(h3, (unsigned)e3.y, a, b4);
        }
        if (i3 + 1 < end) {
            int2 e0 = ls2[i3];
            int2 e1 = ls2[i3 + 1];
            uint4 h0 = hp[(size_t)(e0.x & 0x1FFFF) * 16 + s16];
            uint4 h1 = hp[(size_t)(e1.x & 0x1FFFF) * 16 + s16];
            qfma(h0, (unsigned)e0.y, a, b4);
            qfma(h1, (unsigned)e1.y, a, b4);
            i3 += 2;
        }
        if (i3 < end) {
            int2 e = ls2[i3];
            uint4 h = hp[(size_t)(e.x & 0x1FFFF) * 16 + s16];
            qfma(h, (unsigned)e.y, a, b4);
        }
        ((uint4*)Hout16)[(size_t)row * 16 + s16] =
            make_uint4(packbf(a.x, a.y), packbf(a.z, a.w),
                       packbf(b4.x, b4.y), packbf(b4.z, b4.w));
    }
}

// ---------------------------------------------------------------------------
// Fused layer-2 gather (target rows) + tail MLP. Block = 4 waves = 4 targets.
// (round-5 version, kept verbatim)
// ---------------------------------------------------------------------------
__global__ __launch_bounds__(256) void tgt_tail_kernel(
        const unsigned* __restrict__ Hin16,
        const unsigned* __restrict__ Xp16,
        const int* __restrict__ offs,
        const int2* __restrict__ edataS,
        const float* __restrict__ cw,
        const int* __restrict__ tgt,
        const float* __restrict__ lin1_w,
        const float* __restrict__ lin1_b,
        const float* __restrict__ lin_w,
        const float* __restrict__ lin_b,
        float* __restrict__ out) {
    __shared__ float hc[4][W_INF];
    __shared__ float hmid[4][DD];

    int tid = threadIdx.x;

    float f0a[T_TYPES], f1a[T_TYPES], f0b[T_TYPES], f1b[T_TYPES];
    load_filter(cw, 0, f0a, f1a);
    load_filter(cw, 1, f0b, f1b);
    float r0[T_TYPES], r1[T_TYPES];
    #pragma unroll
    for (int t = 0; t < T_TYPES; ++t) { r0[t] = f0b[t] / f0a[t]; r1[t] = f1b[t] / f1a[t]; }

    int w = tid >> 6, lane = tid & 63;
    int s16 = lane & 15, sub = lane >> 4;
    int m = blockIdx.x * 4 + w;               // M = 10000 = 2500*4
    int row = tgt[m];
    int beg = row_beg(offs, row);
    int end = offs[row];
    const uint4* hp = (const uint4*)Hin16;
    float4 a = make_float4(0.f, 0.f, 0.f, 0.f);
    float4 b = make_float4(0.f, 0.f, 0.f, 0.f);
    for (int i = beg + sub; i < end; i += 4) {
        int2 e = edataS[i];
        int t = (e.x >> 17) & 3;
        uint4 h = hp[(size_t)(e.x & 0x1FFFF) * 16 + s16];
        unsigned wp = (unsigned)e.y;
        float w0 = bflo(wp) * r0[t], w1 = bfhi(wp) * r1[t];
        a.x = fmaf(w0, bflo(h.x), a.x);
        a.y = fmaf(w1, bfhi(h.x), a.y);
        a.z = fmaf(w0, bflo(h.y), a.z);
        a.w = fmaf(w1, bfhi(h.y), a.w);
        b.x = fmaf(w0, bflo(h.z), b.x);
        b.y = fmaf(w1, bfhi(h.z), b.y);
        b.z = fmaf(w0, bflo(h.w), b.z);
        b.w = fmaf(w1, bfhi(h.w), b.w);
    }
    qreduce(a, b);

    if (sub == 0) {
        uint4 xu = ((const uint4*)Xp16)[(size_t)row * 16 + s16];
        int d0 = 4 * s16;
        hc[w][d0 + 0]      = fmaxf(BETA * bflo(xu.x) + (1.f - BETA) * a.x, 0.f);
        hc[w][DD + d0 + 0] = fmaxf(BETA * bfhi(xu.x) + (1.f - BETA) * a.y, 0.f);
        hc[w][d0 + 1]      = fmaxf(BETA * bflo(xu.y) + (1.f - BETA) * a.z, 0.f);
        hc[w][DD + d0 + 1] = fmaxf(BETA * bfhi(xu.y) + (1.f - BETA) * a.w, 0.f);
        hc[w][d0 + 2]      = fmaxf(BETA * bflo(xu.z) + (1.f - BETA) * b.x, 0.f);
        hc[w][DD + d0 + 2] = fmaxf(BETA * bfhi(xu.z) + (1.f - BETA) * b.y, 0.f);
        hc[w][d0 + 3]      = fmaxf(BETA * bflo(xu.w) + (1.f - BETA) * b.z, 0.f);
        hc[w][DD + d0 + 3] = fmaxf(BETA * bfhi(xu.w) + (1.f - BETA) * b.w, 0.f);
    }
    __syncthreads();

    float a1 = lin1_b[lane];
    #pragma unroll 8
    for (int k = 0; k < W_INF; ++k)
        a1 = fmaf(hc[w][k], lin1_w[k * DD + lane], a1);
    hmid[w][lane] = a1;
    __syncthreads();

    if (lane < NUM_CLASS) {
        float o = lin_b[lane];
        #pragma unroll 8
        for (int k = 0; k < DD; ++k)
            o = fmaf(hmid[w][k], lin_w[k * NUM_CLASS + lane], o);
        out[(size_t)m * NUM_CLASS + lane] = o;
    }
}

// ---------------------------------------------------------------------------
extern "C" void kernel_launch(void* const* d_in, const int* in_sizes, int n_in,
                              void* d_out, int out_size, void* d_ws, size_t ws_size,
                              hipStream_t stream) {
    const float* X            = (const float*)d_in[0];
    const float* edge_value   = (const float*)d_in[1];
    const float* conv_weights = (const float*)d_in[2];
    const float* Ws           = (const float*)d_in[3];
    const float* lin1_w       = (const float*)d_in[4];
    const float* lin1_b       = (const float*)d_in[5];
    const float* lin_w        = (const float*)d_in[6];
    const float* lin_b        = (const float*)d_in[7];
    const int*   edge_index   = (const int*)d_in[8];
    const int*   target_x     = (const int*)d_in[9];
    float* out = (float*)d_out;

    unsigned*       Xp16 = (unsigned*)d_ws;                   // 25.6 MB
    unsigned*       H116 = Xp16 + PLANE2;                     // 25.6 MB
    unsigned short* Wsb  = (unsigned short*)(H116 + PLANE2);  // 32 KB
    int*            offs = (int*)(Wsb + C_CH * W_INF * DD);   // N ints
    int*            cursor = offs + N_NODES;                  // 512
    int*            istgt  = cursor + 512;                    // NCNT ints
    int*            need   = istgt + NCNT;                    // NCNT ints
    int2*           edata2 = (int2*)(need + NCNT);            // NBKT*BPAD int2 (15.2 MB)
    int2*           edataS = edata2 + (size_t)NBKT * BPAD;    // NBKT*8*QPAD int2 (16.8 MB)

    hipMemsetAsync(istgt, 0, 2 * NCNT * sizeof(int), stream); // istgt + need
    prep_kernel<<<106, 256, 0, stream>>>(Ws, Wsb, cursor, target_x, istgt);
    build_proj_kernel<<<NPART_BLK + PROJ_BLK, 256, 0, stream>>>(
        edge_index, edge_value, conv_weights, cursor, edata2, X, Wsb, Xp16,
        istgt, need);
    sortgather_kernel<<<8 * 392, 256, 0, stream>>>(cursor, edata2, edataS, offs,
                                                   need, Xp16, H116);
    tgt_tail_kernel<<<M_TGT / 4, 256, 0, stream>>>(H116, Xp16, offs, edataS,
                                                   conv_weights, target_x,
                                                   lin1_w, lin1_b, lin_w, lin_b, out);
}

// Round 12
// 237.010 us; speedup vs baseline: 1.0268x; 1.0268x over previous
//
#include <hip/hip_runtime.h>

// ---- problem constants (from reference) ----
#define N_NODES   100000
#define T_TYPES   4
#define E_EDGES   400000
#define E4        100000                    // int4 groups per type-array
#define G_TOT     400000                    // total int4 groups = TE_TOT/4
#define C_CH      2
#define W_INF     128
#define DD        64
#define NUM_CLASS 16
#define BETA      0.5f
#define M_TGT     10000

// CSR build tiling: 256-row buckets (partition), 32-row octants (sort/gather)
#define NBKT      391                       // ceil(100000/256) buckets of 256 rows
#define BROWS     256
#define BPAD      4864                      // unsorted slots/bucket (mean 4096 +12 sigma)
#define QPAD      672                       // sorted slots/octant (mean 512 +7 sigma)
#define CHUNK_G   1024                      // int4 groups per partition block (4096 edges)
#define NPART_BLK 391                       // ceil(400000/1024): min cursor contention
#define PROJ_BLK  1563                      // ceil(100000/64)
#define MARK_BLK  391                       // need-marking blocks (4096 edges each)
#define SROUND    1024                      // staged-flush slots per round (4 rounds)
#define NCNT      100032                    // istgt/need array size (64-padded)

// bf16 planes: u32 at [n*64 + d] = bf16(ch0) | bf16(ch1)<<16
static const size_t PLANE2 = (size_t)N_NODES * DD;    // u32 elements per plane

typedef __attribute__((ext_vector_type(8))) short short8x;   // 8 bf16 (4 VGPRs)
typedef __attribute__((ext_vector_type(4))) float f32x4;     // MFMA C/D

__device__ __forceinline__ unsigned bf16rne(float x) {   // RNE f32 -> bf16 bits
    unsigned u = __float_as_uint(x);
    return (u + 0x7FFFu + ((u >> 16) & 1u)) >> 16;
}
__device__ __forceinline__ unsigned packbf(float a, float b) {
    return bf16rne(a) | (bf16rne(b) << 16);
}
__device__ __forceinline__ float bflo(unsigned u) { return __uint_as_float(u << 16); }
__device__ __forceinline__ float bfhi(unsigned u) { return __uint_as_float(u & 0xFFFF0000u); }

__device__ __forceinline__ void load_filter(const float* cw, int layer,
                                            float* f0, float* f1) {
    float m0 = -1e30f, m1 = -1e30f;
    #pragma unroll
    for (int t = 0; t < T_TYPES; ++t) {
        f0[t] = cw[layer * C_CH * T_TYPES + t];
        f1[t] = cw[layer * C_CH * T_TYPES + T_TYPES + t];
        m0 = fmaxf(m0, f0[t]); m1 = fmaxf(m1, f1[t]);
    }
    float s0 = 0.f, s1 = 0.f;
    #pragma unroll
    for (int t = 0; t < T_TYPES; ++t) {
        f0[t] = __expf(f0[t] - m0); s0 += f0[t];
        f1[t] = __expf(f1[t] - m1); s1 += f1[t];
    }
    #pragma unroll
    for (int t = 0; t < T_TYPES; ++t) { f0[t] /= s0; f1[t] /= s1; }
}

// ---------------------------------------------------------------------------
// prep: Wsb (blocks 0..63) + cursor init (64..65) + istgt fill (66..105).
// istgt[] / need[] are zeroed by hipMemsetAsync before this kernel.
// ---------------------------------------------------------------------------
__global__ void prep_kernel(const float* __restrict__ Ws,
                            unsigned short* __restrict__ Wsb,
                            int* __restrict__ cursor,
                            const int* __restrict__ tgt,
                            int* __restrict__ istgt) {
    int b = blockIdx.x;
    int tid = threadIdx.x;
    if (b < 64) {
        int idx = b * 256 + tid;
        int c   = idx >> 13;
        int rem = idx & 8191;
        int d   = rem >> 7;
        int k   = rem & 127;
        Wsb[idx] = (unsigned short)bf16rne(Ws[c * (W_INF * DD) + k * DD + d]);
    } else if (b < 66) {
        int idx = (b - 64) * 256 + tid;
        if (idx < NBKT) cursor[idx] = idx * BPAD;
    } else {
        int idx = (b - 66) * 256 + tid;
        if (idx < M_TGT) istgt[tgt[idx]] = 1;
    }
}

// ---------------------------------------------------------------------------
// Fused 3-branch kernel:
//  [0, NPART_BLK): partition 4096 edges each into 256-row buckets
//    (FOUR-ROUND LDS staging, flush loop byte-identical to round 10 -- the
//    round-11 istgt lookup is REMOVED from this critical path).
//  [NPART_BLK, +PROJ_BLK): LDS-free MFMA projection.
//  [+PROJ_BLK, +MARK_BLK): need-marking -- stream rows+cols, if istgt[row]
//    then need[col]=1 (~152k filtered stores; independent latency-hidden
//    work that fills scheduler gaps, NOT on the partition critical path).
// record: edata2[pos] = { col | t<<17 | (row&255)<<19 ,
//                         packbf(val*f0_l1[t], val*f1_l1[t]) }
// ---------------------------------------------------------------------------
__global__ __launch_bounds__(256) void build_proj_kernel(
        const int* __restrict__ edge_index,
        const float* __restrict__ edge_value,
        const float* __restrict__ cw,
        int* __restrict__ cursor,
        int2* __restrict__ edata2,
        const float* __restrict__ X,
        const unsigned short* __restrict__ Wsb,
        unsigned* __restrict__ Xp16,
        const int* __restrict__ istgt,
        int* __restrict__ need) {
    __shared__ int cnt[392];
    __shared__ int lbase[392];
    __shared__ int gbase[392];
    __shared__ int2 le[SROUND];                   // 8 KB (reused per round)
    __shared__ unsigned short lbk[SROUND];        // 2 KB
    int tid = threadIdx.x;

    if (blockIdx.x < NPART_BLK) {
        // ---------------- partition ----------------
        int p = blockIdx.x;
        for (int j = tid; j < NBKT; j += 256) cnt[j] = 0;
        __syncthreads();

        float f0[T_TYPES], f1[T_TYPES];
        load_filter(cw, 0, f0, f1);

        int px[16], pv[16], rk[16], bk[16];
        int ne = 0;
        #pragma unroll
        for (int g = 0; g < 4; ++g) {
            int idx = p * CHUNK_G + g * 256 + tid;
            if (idx < G_TOT) {
                int t = idx / E4, r = idx - t * E4;
                const int* bptr = edge_index + (size_t)t * 2 * E_EDGES;
                int4   rw = ((const int4*)bptr)[r];
                int4   cl = ((const int4*)(bptr + E_EDGES))[r];
                float4 vv = ((const float4*)(edge_value + (size_t)t * E_EDGES))[r];
                int tb = t << 17;
                int   rr[4] = {rw.x, rw.y, rw.z, rw.w};
                int   cc[4] = {cl.x, cl.y, cl.z, cl.w};
                float vf[4] = {vv.x, vv.y, vv.z, vv.w};
                #pragma unroll
                for (int k = 0; k < 4; ++k) {
                    int b = rr[k] >> 8;
                    px[ne] = cc[k] | tb | ((rr[k] & 255) << 19);
                    pv[ne] = __float_as_int(vf[k]);
                    bk[ne] = b;
                    rk[ne] = atomicAdd(&cnt[b], 1);
                    ++ne;
                }
            }
        }
        __syncthreads();
        if (tid < 64) {                                // scan cnt -> lbase (7/lane)
            int c[7]; int s = 0;
            #pragma unroll
            for (int k = 0; k < 7; ++k) {
                int idx = tid * 7 + k;
                c[k] = (idx < NBKT) ? cnt[idx] : 0;
                s += c[k];
            }
            int inc = s;
            #pragma unroll
            for (int off = 1; off < 64; off <<= 1) {
                int v = __shfl_up(inc, off);
                if (tid >= off) inc += v;
            }
            int base = inc - s;
            #pragma unroll
            for (int k = 0; k < 7; ++k) {
                int idx = tid * 7 + k;
                if (idx < NBKT) lbase[idx] = base;
                base += c[k];
            }
        }
        __syncthreads();
        for (int j = tid; j < NBKT; j += 256)
            gbase[j] = cnt[j] ? atomicAdd(&cursor[j], cnt[j]) : 0;
        __syncthreads();

        int ngrp = min(CHUNK_G, G_TOT - p * CHUNK_G);
        int nloc = 4 * ngrp;
        #pragma unroll
        for (int rd = 0; rd < 4; ++rd) {
            int lo = rd * SROUND;
            // stage this round's slot range
            #pragma unroll
            for (int k = 0; k < 16; ++k) {
                if (k < ne) {
                    int slot = lbase[bk[k]] + rk[k] - lo;
                    if ((unsigned)slot < (unsigned)SROUND) {
                        le[slot]  = make_int2(px[k], pv[k]);
                        lbk[slot] = (unsigned short)bk[k];
                    }
                }
            }
            __syncthreads();
            int nthis = min(SROUND, nloc - lo);
            for (int j = tid; j < nthis; j += 256) {
                int b = lbk[j];
                int2 e = le[j];
                int t = (e.x >> 17) & 3;
                float v = __int_as_float(e.y);
                edata2[gbase[b] + (lo + j - lbase[b])] =
                    make_int2(e.x, (int)packbf(v * f0[t], v * f1[t]));
            }
            __syncthreads();
        }
    } else if (blockIdx.x < NPART_BLK + PROJ_BLK) {
        // ---------------- MFMA projection (LDS-free) ----------------
        int row0 = (blockIdx.x - NPART_BLK) * 64;
        int wave = tid >> 6, lane = tid & 63;
        int m = lane & 15, q = lane >> 4;
        int arow = row0 + wave * 16 + m;
        const float4* X4 = (const float4*)X;
        union { short8x s; uint4 u; } A[4];
        bool valid = arow < N_NODES;
        #pragma unroll
        for (int ks = 0; ks < 4; ++ks) {
            float4 va = make_float4(0.f, 0.f, 0.f, 0.f), vb = va;
            if (valid) {
                va = X4[(size_t)arow * 32 + ks * 8 + q * 2];
                vb = X4[(size_t)arow * 32 + ks * 8 + q * 2 + 1];
            }
            A[ks].u = make_uint4(packbf(va.x, va.y), packbf(va.z, va.w),
                                 packbf(vb.x, vb.y), packbf(vb.z, vb.w));
        }

        #pragma unroll
        for (int ct = 0; ct < 4; ++ct) {
            f32x4 acc0 = {0.f, 0.f, 0.f, 0.f};
            f32x4 acc1 = {0.f, 0.f, 0.f, 0.f};
            #pragma unroll
            for (int ks = 0; ks < 4; ++ks) {
                short8x B0 = *(const short8x*)(Wsb + (ct * 16 + m) * 128 + ks * 32 + q * 8);
                short8x B1 = *(const short8x*)(Wsb + 8192 + (ct * 16 + m) * 128 + ks * 32 + q * 8);
                acc0 = __builtin_amdgcn_mfma_f32_16x16x32_bf16(A[ks].s, B0, acc0, 0, 0, 0);
                acc1 = __builtin_amdgcn_mfma_f32_16x16x32_bf16(A[ks].s, B1, acc1, 0, 0, 0);
            }
            #pragma unroll
            for (int r = 0; r < 4; ++r) {
                int row = row0 + wave * 16 + q * 4 + r;
                if (row < N_NODES)
                    Xp16[(size_t)row * DD + ct * 16 + m] = packbf(acc0[r], acc1[r]);
            }
        }
    } else {
        // ---------------- need-marking (off critical path) ----------------
        int p = blockIdx.x - NPART_BLK - PROJ_BLK;
        #pragma unroll
        for (int g = 0; g < 4; ++g) {
            int idx = p * CHUNK_G + g * 256 + tid;
            if (idx < G_TOT) {
                int t = idx / E4, r = idx - t * E4;
                const int* bptr = edge_index + (size_t)t * 2 * E_EDGES;
                int4 rw = ((const int4*)bptr)[r];
                int4 cl = ((const int4*)(bptr + E_EDGES))[r];
                if (istgt[rw.x]) need[cl.x] = 1;
                if (istgt[rw.y]) need[cl.y] = 1;
                if (istgt[rw.z]) need[cl.z] = 1;
                if (istgt[rw.w]) need[cl.w] = 1;
            }
        }
    }
}

// ---------------------------------------------------------------------------
// Quarter-wave bf16 gather helpers
// ---------------------------------------------------------------------------
__device__ __forceinline__ void qfma(const uint4 h, unsigned wp,
                                     float4& a, float4& b) {
    float w0 = bflo(wp), w1 = bfhi(wp);
    a.x = fmaf(w0, bflo(h.x), a.x);
    a.y = fmaf(w1, bfhi(h.x), a.y);
    a.z = fmaf(w0, bflo(h.y), a.z);
    a.w = fmaf(w1, bfhi(h.y), a.w);
    b.x = fmaf(w0, bflo(h.z), b.x);
    b.y = fmaf(w1, bfhi(h.z), b.y);
    b.z = fmaf(w0, bflo(h.w), b.z);
    b.w = fmaf(w1, bfhi(h.w), b.w);
}

__device__ __forceinline__ void qreduce(float4& a, float4& b) {
    a.x += __shfl_xor(a.x, 16); a.y += __shfl_xor(a.y, 16);
    a.z += __shfl_xor(a.z, 16); a.w += __shfl_xor(a.w, 16);
    b.x += __shfl_xor(b.x, 16); b.y += __shfl_xor(b.y, 16);
    b.z += __shfl_xor(b.z, 16); b.w += __shfl_xor(b.w, 16);
    a.x += __shfl_xor(a.x, 32); a.y += __shfl_xor(a.y, 32);
    a.z += __shfl_xor(a.z, 32); a.w += __shfl_xor(a.w, 32);
    b.x += __shfl_xor(b.x, 32); b.y += __shfl_xor(b.y, 32);
    b.z += __shfl_xor(b.z, 32); b.w += __shfl_xor(b.w, 32);
}

__device__ __forceinline__ int row_beg(const int* offs, int row) {
    return ((row & 31) == 0) ? (row >> 5) * QPAD : offs[row - 1];
}

// ---------------------------------------------------------------------------
// Per-OCTANT (32 rows of a 256-row bucket) sort + layer-1 gather.
// XCD-affine temporal interleave (round 10) + need[]-gated gather (round 11).
// Sort, edataS write-back and offs stay exact for ALL rows.
// ---------------------------------------------------------------------------
__global__ __launch_bounds__(256) void sortgather_kernel(
        const int* __restrict__ cursor,
        const int2* __restrict__ edata2,
        int2* __restrict__ edataS,
        int* __restrict__ offs,
        const int* __restrict__ need,
        const unsigned* __restrict__ Hin16,
        unsigned* __restrict__ Hout16) {
    __shared__ int rcnt[32];
    __shared__ int rbase[32];
    __shared__ int rcur[32];
    __shared__ int nq;
    __shared__ int2 ls[QPAD];                     // 5376 B
    __shared__ int2 ls2[QPAD];                    // 5376 B (sorted)
    int i = blockIdx.x;
    int b = (i & 7) + ((i >> 6) << 3);            // bucket: same XCD, 8 consecutive slots
    int o = (i >> 3) & 7;                         // octant
    if (b >= NBKT) return;
    int tid = threadIdx.x;
    int bb  = b * BPAD;
    int cnt = cursor[b] - bb;

    if (tid < 32) rcnt[tid] = 0;
    if (tid == 0) nq = 0;
    __syncthreads();
    for (int j = tid; j < cnt; j += 256) {
        int2 e = edata2[bb + j];
        int rt = (e.x >> 19) & 255;
        if ((rt >> 5) == o) {
            int pos = atomicAdd(&nq, 1);
            if (pos < QPAD) {
                ls[pos] = e;
                atomicAdd(&rcnt[rt & 31], 1);
            }
        }
    }
    __syncthreads();
    int nl = min(nq, QPAD);
    if (tid < 32) {                                // scan 32 row counts (wave 0)
        int c = rcnt[tid];
        int inc = c;
        #pragma unroll
        for (int off = 1; off < 32; off <<= 1) {
            int v = __shfl_up(inc, off);
            if (tid >= off) inc += v;
        }
        rbase[tid] = inc - c;
        rcur[tid]  = inc - c;
    }
    __syncthreads();
    for (int j = tid; j < nl; j += 256) {
        int2 e = ls[j];
        int lr = (e.x >> 19) & 31;
        int pos = atomicAdd(&rcur[lr], 1);
        ls2[pos] = e;
    }
    __syncthreads();

    int s  = b * 8 + o;                           // global 32-row octant id
    int sb = s * QPAD;
    for (int i2 = tid; i2 < nl; i2 += 256)        // coalesced sorted write-back
        edataS[sb + i2] = ls2[i2];
    int row0 = s * 32;
    if (tid < 32 && row0 + tid < N_NODES)
        offs[row0 + tid] = sb + rbase[tid] + rcnt[tid];
    __syncthreads();

    // ---- layer-1 gather: quarter-per-row, need[]-gated ----
    int wv = tid >> 6, lane = tid & 63;
    int s16 = lane & 15, qd = lane >> 4;
    const uint4* hp = (const uint4*)Hin16;
    #pragma unroll
    for (int rr = 0; rr < 2; ++rr) {
        int lr  = wv * 8 + rr * 4 + qd;
        int row = row0 + lr;
        if (row >= N_NODES || !need[row]) continue;   // H1 never consumed
        int beg = rbase[lr];
        int end = beg + rcnt[lr];
        float4 a  = make_float4(0.f, 0.f, 0.f, 0.f);
        float4 b4 = make_float4(0.f, 0.f, 0.f, 0.f);
        int i3 = beg;
        for (; i3 + 3 < end; i3 += 4) {
            int2 e0 = ls2[i3], e1 = ls2[i3 + 1], e2 = ls2[i3 + 2], e3 = ls2[i3 + 3];
            uint4 h0 = hp[(size_t)(e0.x & 0x1FFFF) * 16 + s16];
            uint4 h1 = hp[(size_t)(e1.x & 0x1FFFF) * 16 + s16];
            uint4 h2 = hp[(size_t)(e2.x & 0x1FFFF) * 16 + s16];
            uint4 h3 = hp[(size_t)(e3.x & 0x1FFFF) * 16 + s16];
            qfma(h0, (unsigned)e0.y, a, b4);
            qfma(h1, (unsigned)e1.y, a, b4);
            qfma(h2, (unsigned)e2.y, a, b4);
            qfma(h3, (unsigned)e3.y, a, b4);
        }
        if (i3 + 1 < end) {
            int2 e0 = ls2[i3];
            int2 e1 = ls2[i3 + 1];
            uint4 h0 = hp[(size_t)(e0.x & 0x1FFFF) * 16 + s16];
            uint4 h1 = hp[(size_t)(e1.x & 0x1FFFF) * 16 + s16];
            qfma(h0, (unsigned)e0.y, a, b4);
            qfma(h1, (unsigned)e1.y, a, b4);
            i3 += 2;
        }
        if (i3 < end) {
            int2 e = ls2[i3];
            uint4 h = hp[(size_t)(e.x & 0x1FFFF) * 16 + s16];
            qfma(h, (unsigned)e.y, a, b4);
        }
        ((uint4*)Hout16)[(size_t)row * 16 + s16] =
            make_uint4(packbf(a.x, a.y), packbf(a.z, a.w),
                       packbf(b4.x, b4.y), packbf(b4.z, b4.w));
    }
}

// ---------------------------------------------------------------------------
// Fused layer-2 gather (target rows) + tail MLP. Block = 4 waves = 4 targets.
// (round-5 version, kept verbatim)
// ---------------------------------------------------------------------------
__global__ __launch_bounds__(256) void tgt_tail_kernel(
        const unsigned* __restrict__ Hin16,
        const unsigned* __restrict__ Xp16,
        const int* __restrict__ offs,
        const int2* __restrict__ edataS,
        const float* __restrict__ cw,
        const int* __restrict__ tgt,
        const float* __restrict__ lin1_w,
        const float* __restrict__ lin1_b,
        const float* __restrict__ lin_w,
        const float* __restrict__ lin_b,
        float* __restrict__ out) {
    __shared__ float hc[4][W_INF];
    __shared__ float hmid[4][DD];

    int tid = threadIdx.x;

    float f0a[T_TYPES], f1a[T_TYPES], f0b[T_TYPES], f1b[T_TYPES];
    load_filter(cw, 0, f0a, f1a);
    load_filter(cw, 1, f0b, f1b);
    float r0[T_TYPES], r1[T_TYPES];
    #pragma unroll
    for (int t = 0; t < T_TYPES; ++t) { r0[t] = f0b[t] / f0a[t]; r1[t] = f1b[t] / f1a[t]; }

    int w = tid >> 6, lane = tid & 63;
    int s16 = lane & 15, sub = lane >> 4;
    int m = blockIdx.x * 4 + w;               // M = 10000 = 2500*4
    int row = tgt[m];
    int beg = row_beg(offs, row);
    int end = offs[row];
    const uint4* hp = (const uint4*)Hin16;
    float4 a = make_float4(0.f, 0.f, 0.f, 0.f);
    float4 b = make_float4(0.f, 0.f, 0.f, 0.f);
    for (int i = beg + sub; i < end; i += 4) {
        int2 e = edataS[i];
        int t = (e.x >> 17) & 3;
        uint4 h = hp[(size_t)(e.x & 0x1FFFF) * 16 + s16];
        unsigned wp = (unsigned)e.y;
        float w0 = bflo(wp) * r0[t], w1 = bfhi(wp) * r1[t];
        a.x = fmaf(w0, bflo(h.x), a.x);
        a.y = fmaf(w1, bfhi(h.x), a.y);
        a.z = fmaf(w0, bflo(h.y), a.z);
        a.w = fmaf(w1, bfhi(h.y), a.w);
        b.x = fmaf(w0, bflo(h.z), b.x);
        b.y = fmaf(w1, bfhi(h.z), b.y);
        b.z = fmaf(w0, bflo(h.w), b.z);
        b.w = fmaf(w1, bfhi(h.w), b.w);
    }
    qreduce(a, b);

    if (sub == 0) {
        uint4 xu = ((const uint4*)Xp16)[(size_t)row * 16 + s16];
        int d0 = 4 * s16;
        hc[w][d0 + 0]      = fmaxf(BETA * bflo(xu.x) + (1.f - BETA) * a.x, 0.f);
        hc[w][DD + d0 + 0] = fmaxf(BETA * bfhi(xu.x) + (1.f - BETA) * a.y, 0.f);
        hc[w][d0 + 1]      = fmaxf(BETA * bflo(xu.y) + (1.f - BETA) * a.z, 0.f);
        hc[w][DD + d0 + 1] = fmaxf(BETA * bfhi(xu.y) + (1.f - BETA) * a.w, 0.f);
        hc[w][d0 + 2]      = fmaxf(BETA * bflo(xu.z) + (1.f - BETA) * b.x, 0.f);
        hc[w][DD + d0 + 2] = fmaxf(BETA * bfhi(xu.z) + (1.f - BETA) * b.y, 0.f);
        hc[w][d0 + 3]      = fmaxf(BETA * bflo(xu.w) + (1.f - BETA) * b.z, 0.f);
        hc[w][DD + d0 + 3] = fmaxf(BETA * bfhi(xu.w) + (1.f - BETA) * b.w, 0.f);
    }
    __syncthreads();

    float a1 = lin1_b[lane];
    #pragma unroll 8
    for (int k = 0; k < W_INF; ++k)
        a1 = fmaf(hc[w][k], lin1_w[k * DD + lane], a1);
    hmid[w][lane] = a1;
    __syncthreads();

    if (lane < NUM_CLASS) {
        float o = lin_b[lane];
        #pragma unroll 8
        for (int k = 0; k < DD; ++k)
            o = fmaf(hmid[w][k], lin_w[k * NUM_CLASS + lane], o);
        out[(size_t)m * NUM_CLASS + lane] = o;
    }
}

// ---------------------------------------------------------------------------
extern "C" void kernel_launch(void* const* d_in, const int* in_sizes, int n_in,
                              void* d_out, int out_size, void* d_ws, size_t ws_size,
                              hipStream_t stream) {
    const float* X            = (const float*)d_in[0];
    const float* edge_value   = (const float*)d_in[1];
    const float* conv_weights = (const float*)d_in[2];
    const float* Ws           = (const float*)d_in[3];
    const float* lin1_w       = (const float*)d_in[4];
    const float* lin1_b       = (const float*)d_in[5];
    const float* lin_w        = (const float*)d_in[6];
    const float* lin_b        = (const float*)d_in[7];
    const int*   edge_index   = (const int*)d_in[8];
    const int*   target_x     = (const int*)d_in[9];
    float* out = (float*)d_out;

    unsigned*       Xp16 = (unsigned*)d_ws;                   // 25.6 MB
    unsigned*       H116 = Xp16 + PLANE2;                     // 25.6 MB
    unsigned short* Wsb  = (unsigned short*)(H116 + PLANE2);  // 32 KB
    int*            offs = (int*)(Wsb + C_CH * W_INF * DD);   // N ints
    int*            cursor = offs + N_NODES;                  // 512
    int*            istgt  = cursor + 512;                    // NCNT ints
    int*            need   = istgt + NCNT;                    // NCNT ints
    int2*           edata2 = (int2*)(need + NCNT);            // NBKT*BPAD int2 (15.2 MB)
    int2*           edataS = edata2 + (size_t)NBKT * BPAD;    // NBKT*8*QPAD int2 (16.8 MB)

    hipMemsetAsync(istgt, 0, 2 * NCNT * sizeof(int), stream); // istgt + need
    prep_kernel<<<106, 256, 0, stream>>>(Ws, Wsb, cursor, target_x, istgt);
    build_proj_kernel<<<NPART_BLK + PROJ_BLK + MARK_BLK, 256, 0, stream>>>(
        edge_index, edge_value, conv_weights, cursor, edata2, X, Wsb, Xp16,
        istgt, need);
    sortgather_kernel<<<8 * 392, 256, 0, stream>>>(cursor, edata2, edataS, offs,
                                                   need, Xp16, H116);
    tgt_tail_kernel<<<M_TGT / 4, 256, 0, stream>>>(H116, Xp16, offs, edataS,
                                                   conv_weights, target_x,
                                                   lin1_w, lin1_b, lin_w, lin_b, out);
}